// Round 6
// baseline (169.586 us; speedup 1.0000x reference)
//
#include <hip/hip_runtime.h>

// ChannelAttention fused kernel for MI355X (gfx950), round 5.
// B=4, L=16384, C=128, H=8, hd=16. Tokens M = 65536.
//
// R5 change vs R4: occupancy is the binding constraint (8.3 waves/CU resident,
// all pipes <35%). qkv LDS back to bf16 -> 25 KB -> 6 blocks/CU cap (24
// waves/CU, 2x R4). Conversions stay cheap: transpose = add+ds_write_b16
// (d16_hi), stage-B unpack = 1 VALU/elem. __launch_bounds__(256,6) (85-reg
// cap; natural usage was 72). Stage-A staging restructured per-m and weight
// batches of 3 to fit the cap without spill.
//
// Per 32-token block (4 waves):
//   stage A: wave owns 6 n-tiles x both m-tiles; batched weight loads (3s),
//            each bfrag feeds 2 MFMAs; bias folded into acc init.
//   transpose: qkv -> LDS bf16 [32][392]
//   stage B: thread owns (t = tid&31, h = tid>>5); 6x ds_read_b128 packed;
//            attention fully in-register fp32: 256 exp2 + fma; no cross-lane.
//   stage C: o -> LDS bf16 (stride 136, overlaps qkv region after barrier),
//            out = o @ Wproj + b via MFMA, fp32 store.
// Weights pre-transposed+bf16 in d_ws: [N][K] so B-frags are 16B loads.

typedef __attribute__((ext_vector_type(8))) short bf16x8;
typedef __attribute__((ext_vector_type(4))) float f32x4;
typedef __attribute__((ext_vector_type(4))) unsigned int u32x4;

#define TILE_M 32
#define QKV_STRIDE 392   // bf16 elems per token row (>=384); 784 B rows, 16B aligned
#define O_STRIDE 136     // bf16 elems per o row

__device__ __forceinline__ unsigned short f2bf(float f) {
    unsigned int u = __builtin_bit_cast(unsigned int, f);
    u += 0x8000u;                      // round half up
    return (unsigned short)(u >> 16);
}
// pack two floats -> packed bf16x2 (lo in low short) in 3 VALU ops
__device__ __forceinline__ unsigned int pkbf(float lo, float hi) {
    unsigned int a = __builtin_bit_cast(unsigned int, lo) + 0x8000u;
    unsigned int b = __builtin_bit_cast(unsigned int, hi) + 0x8000u;
    return __builtin_amdgcn_perm(b, a, 0x07060302u);  // {hi16(b),hi16(a)}
}
__device__ __forceinline__ float bflo(unsigned int u) {
    return __builtin_bit_cast(float, u << 16);
}
__device__ __forceinline__ float bfhi(unsigned int u) {
    return __builtin_bit_cast(float, u & 0xffff0000u);
}

__global__ void prep_weights(const float* __restrict__ wqkv,
                             const float* __restrict__ wproj,
                             unsigned short* __restrict__ wqkvT,
                             unsigned short* __restrict__ wprojT) {
    int idx = blockIdx.x * 256 + threadIdx.x;
    if (idx < 384 * 128) {               // wqkvT[n][k] = bf16(wqkv[k][n])
        int n = idx >> 7, k = idx & 127;
        wqkvT[idx] = f2bf(wqkv[k * 384 + n]);
    }
    if (idx < 128 * 128) {               // wprojT[n][k] = bf16(wproj[k][n])
        int n = idx >> 7, k = idx & 127;
        wprojT[idx] = f2bf(wproj[k * 128 + n]);
    }
}

__global__ __launch_bounds__(256, 6) void fused_channel_attn(
    const float* __restrict__ x,
    const unsigned short* __restrict__ wqkvT,
    const float* __restrict__ bqkv,
    const unsigned short* __restrict__ wprojT,
    const float* __restrict__ bproj,
    float* __restrict__ out)
{
    __shared__ __align__(16) unsigned short us[TILE_M * QKV_STRIDE];  // 25088 B

    const int tid  = threadIdx.x;
    const int lane = tid & 63;
    const int wave = tid >> 6;
    const int col  = lane & 15;   // MFMA C/D col == A row (m) == B col (n)
    const int quad = lane >> 4;
    const long base_tok = (long)blockIdx.x * TILE_M;

    const int nb = wave * 6;      // this wave's 6 qkv n-tiles (both m-tiles)

    // ---- stage A: x fragments, per-m rounds (8 loads in flight, low reg peak)
    bf16x8 afr[2][4];
#pragma unroll
    for (int m = 0; m < 2; ++m) {
        const float* xrow = x + (base_tok + m * 16 + col) * 128;
        float4 s[4][2];
#pragma unroll
        for (int ks = 0; ks < 4; ++ks) {
            const float4* p = (const float4*)(xrow + ks * 32 + quad * 8);
            s[ks][0] = p[0];
            s[ks][1] = p[1];
        }
#pragma unroll
        for (int ks = 0; ks < 4; ++ks) {
            float4 f0 = s[ks][0], f1 = s[ks][1];
            u32x4 a = {pkbf(f0.x, f0.y), pkbf(f0.z, f0.w),
                       pkbf(f1.x, f1.y), pkbf(f1.z, f1.w)};
            afr[m][ks] = __builtin_bit_cast(bf16x8, a);
        }
    }

    // acc[m][j][r] = qkv[m*16 + quad*4 + r][(nb+j)*16 + col]; init = bias
    f32x4 acc[2][6];
#pragma unroll
    for (int j = 0; j < 6; ++j) {
        float b = bqkv[(nb + j) * 16 + col];
        acc[0][j] = (f32x4){b, b, b, b};
        acc[1][j] = (f32x4){b, b, b, b};
    }
#pragma unroll
    for (int ks = 0; ks < 4; ++ks) {
#pragma unroll
        for (int half = 0; half < 2; ++half) {
            bf16x8 bfr[3];             // batches of 3: MLP without blowing regs
#pragma unroll
            for (int j = 0; j < 3; ++j)
                bfr[j] = *(const bf16x8*)&wqkvT[((nb + half * 3 + j) * 16 + col) * 128 + ks * 32 + quad * 8];
#pragma unroll
            for (int j = 0; j < 3; ++j) {
                int jj = half * 3 + j;
                acc[0][jj] = __builtin_amdgcn_mfma_f32_16x16x32_bf16(afr[0][ks], bfr[j], acc[0][jj], 0, 0, 0);
                acc[1][jj] = __builtin_amdgcn_mfma_f32_16x16x32_bf16(afr[1][ks], bfr[j], acc[1][jj], 0, 0, 0);
            }
        }
    }

    // ---- transpose: qkv -> LDS bf16 [tok][ch] (add + ds_write_b16_d16_hi)
#pragma unroll
    for (int m = 0; m < 2; ++m)
#pragma unroll
        for (int j = 0; j < 6; ++j)
#pragma unroll
            for (int r = 0; r < 4; ++r)
                us[(m * 16 + quad * 4 + r) * QKV_STRIDE + (nb + j) * 16 + col] = f2bf(acc[m][j][r]);
    __syncthreads();

    // ---- stage B: thread owns (t = tid&31, h = tid>>5)
    const int t = tid & 31;
    const int h = tid >> 5;
    const unsigned short* row = us + t * QKV_STRIDE + h * 16;

    u32x4 qp0 = *(const u32x4*)(row);
    u32x4 qp1 = *(const u32x4*)(row + 8);
    u32x4 kp0 = *(const u32x4*)(row + 128);
    u32x4 kp1 = *(const u32x4*)(row + 136);
    u32x4 vp0 = *(const u32x4*)(row + 256);
    u32x4 vp1 = *(const u32x4*)(row + 264);
    __syncthreads();   // all qkv reads done before o writes (regions overlap)

    const float sl2e = 0.08838834764831845f * 1.44269504088896340f; // scale*log2(e)
    float qv[16], kf[16], vf[16];
#pragma unroll
    for (int c = 0; c < 4; ++c) {
        qv[2*c]     = bflo(qp0[c]); qv[2*c+1]     = bfhi(qp0[c]);
        qv[8+2*c]   = bflo(qp1[c]); qv[8+2*c+1]   = bfhi(qp1[c]);
        kf[2*c]     = bflo(kp0[c]); kf[2*c+1]     = bfhi(kp0[c]);
        kf[8+2*c]   = bflo(kp1[c]); kf[8+2*c+1]   = bfhi(kp1[c]);
        vf[2*c]     = bflo(vp0[c]); vf[2*c+1]     = bfhi(vp0[c]);
        vf[8+2*c]   = bflo(vp1[c]); vf[8+2*c+1]   = bfhi(vp1[c]);
    }
    float ov[16];
#pragma unroll
    for (int i = 0; i < 16; ++i) {
        float qs = qv[i] * sl2e;
        float den = 0.f, num = 0.f;
#pragma unroll
        for (int j = 0; j < 16; ++j) {
            float e = __builtin_amdgcn_exp2f(qs * kf[j]);
            den += e;
            num = fmaf(e, vf[j], num);
        }
        ov[i] = num * __builtin_amdgcn_rcpf(den);
    }
    // pack o -> bf16 (8 perms) and store 2x b128 to LDS A-layout (stride 136)
    u32x4 o0 = {pkbf(ov[0], ov[1]), pkbf(ov[2], ov[3]), pkbf(ov[4], ov[5]), pkbf(ov[6], ov[7])};
    u32x4 o1 = {pkbf(ov[8], ov[9]), pkbf(ov[10], ov[11]), pkbf(ov[12], ov[13]), pkbf(ov[14], ov[15])};
    *(u32x4*)&us[t * O_STRIDE + h * 16]     = o0;
    *(u32x4*)&us[t * O_STRIDE + h * 16 + 8] = o1;
    __syncthreads();

    // ---- stage C: out = o @ Wproj + b. Wave: 2 n-tiles x 2 m-tiles.
    const int nb2 = wave * 2;
    bf16x8 af2[2][4];
#pragma unroll
    for (int m = 0; m < 2; ++m)
#pragma unroll
        for (int ks = 0; ks < 4; ++ks)
            af2[m][ks] = *(const bf16x8*)&us[(m * 16 + col) * O_STRIDE + ks * 32 + quad * 8];

    f32x4 acc2[2][2];
#pragma unroll
    for (int n = 0; n < 2; ++n) {
        float b = bproj[(nb2 + n) * 16 + col];
        acc2[0][n] = (f32x4){b, b, b, b};
        acc2[1][n] = (f32x4){b, b, b, b};
    }
#pragma unroll
    for (int ks = 0; ks < 4; ++ks) {
        bf16x8 bb[2];
#pragma unroll
        for (int n = 0; n < 2; ++n)
            bb[n] = *(const bf16x8*)&wprojT[((nb2 + n) * 16 + col) * 128 + ks * 32 + quad * 8];
#pragma unroll
        for (int n = 0; n < 2; ++n) {
            acc2[0][n] = __builtin_amdgcn_mfma_f32_16x16x32_bf16(af2[0][ks], bb[n], acc2[0][n], 0, 0, 0);
            acc2[1][n] = __builtin_amdgcn_mfma_f32_16x16x32_bf16(af2[1][ks], bb[n], acc2[1][n], 0, 0, 0);
        }
    }
#pragma unroll
    for (int m = 0; m < 2; ++m)
#pragma unroll
        for (int n = 0; n < 2; ++n)
#pragma unroll
            for (int r = 0; r < 4; ++r) {
                long tt = base_tok + m * 16 + quad * 4 + r;
                out[tt * 128 + (nb2 + n) * 16 + col] = acc2[m][n][r];
            }
}

extern "C" void kernel_launch(void* const* d_in, const int* in_sizes, int n_in,
                              void* d_out, int out_size, void* d_ws, size_t ws_size,
                              hipStream_t stream) {
    const float* x     = (const float*)d_in[0];
    const float* wqkv  = (const float*)d_in[1];
    const float* bqkv  = (const float*)d_in[2];
    const float* wproj = (const float*)d_in[3];
    const float* bproj = (const float*)d_in[4];
    float* out = (float*)d_out;

    unsigned short* wqkvT  = (unsigned short*)d_ws;    // 384*128 bf16
    unsigned short* wprojT = wqkvT + 384 * 128;        // 128*128 bf16

    prep_weights<<<192, 256, 0, stream>>>(wqkv, wproj, wqkvT, wprojT);

    const int tokens = in_sizes[0] / 128;              // 65536
    fused_channel_attn<<<tokens / TILE_M, 256, 0, stream>>>(
        x, wqkvT, bqkv, wprojT, bproj, out);
}

// Round 7
// 152.983 us; speedup vs baseline: 1.1085x; 1.1085x over previous
//
#include <hip/hip_runtime.h>

// ChannelAttention for MI355X (gfx950), round 6: two-kernel split.
// B=4, L=16384, C=128, H=8, hd=16. Tokens M = 65536.
//
// R6 vs R5: the fused monolith is structurally latency-bound (3 barriers,
// serial stage chain, allocator caps ~72 VGPR; R5's occupancy push spilled).
// Split:
//   k1 qkv_attn: qkv = x@Wqkv+b (MFMA) -> LDS transpose (1 barrier) ->
//      per-(token,head) fp32 softmax-attention -> bf16 o stored to global.
//      o lives INSIDE d_out: first 256 B of each token's 512 B fp32 row
//      (block-disjoint in k2, stream-ordered; no ws_size assumption).
//   k2 proj: out = o@Wproj+b. Streaming GEMM, o tile staged LDS (stride 136),
//      weights from L2. Memory-bound.
// Weights pre-transposed+bf16 in d_ws ([N][K] -> B-frags are 16B loads).

typedef __attribute__((ext_vector_type(8))) short bf16x8;
typedef __attribute__((ext_vector_type(4))) float f32x4;
typedef __attribute__((ext_vector_type(4))) unsigned int u32x4;

#define TILE_M 32        // k1 tokens per block
#define QKV_STRIDE 392   // bf16 elems per k1 LDS row (>=384); 784B rows, 16B aligned
#define PTILE 64         // k2 tokens per block
#define O_STRIDE 136     // k2 LDS row stride (bf16 elems): 68 words/row = 4 mod 32

__device__ __forceinline__ unsigned short f2bf(float f) {
    unsigned int u = __builtin_bit_cast(unsigned int, f);
    u += 0x8000u;                      // round half up
    return (unsigned short)(u >> 16);
}
// pack two floats -> packed bf16x2 (lo in low short) in 3 VALU ops
__device__ __forceinline__ unsigned int pkbf(float lo, float hi) {
    unsigned int a = __builtin_bit_cast(unsigned int, lo) + 0x8000u;
    unsigned int b = __builtin_bit_cast(unsigned int, hi) + 0x8000u;
    return __builtin_amdgcn_perm(b, a, 0x07060302u);  // {hi16(b),hi16(a)}
}
__device__ __forceinline__ float bflo(unsigned int u) {
    return __builtin_bit_cast(float, u << 16);
}
__device__ __forceinline__ float bfhi(unsigned int u) {
    return __builtin_bit_cast(float, u & 0xffff0000u);
}

__global__ void prep_weights(const float* __restrict__ wqkv,
                             const float* __restrict__ wproj,
                             unsigned short* __restrict__ wqkvT,
                             unsigned short* __restrict__ wprojT) {
    int idx = blockIdx.x * 256 + threadIdx.x;
    if (idx < 384 * 128) {               // wqkvT[n][k] = bf16(wqkv[k][n])
        int n = idx >> 7, k = idx & 127;
        wqkvT[idx] = f2bf(wqkv[k * 384 + n]);
    }
    if (idx < 128 * 128) {               // wprojT[n][k] = bf16(wproj[k][n])
        int n = idx >> 7, k = idx & 127;
        wprojT[idx] = f2bf(wproj[k * 128 + n]);
    }
}

// ---------------- kernel 1: qkv GEMM + channel attention ----------------
__global__ __launch_bounds__(256, 4) void qkv_attn(
    const float* __restrict__ x,
    const unsigned short* __restrict__ wqkvT,
    const float* __restrict__ bqkv,
    char* __restrict__ obuf)          // = (char*)d_out; o row t at byte t*512
{
    __shared__ __align__(16) unsigned short us[TILE_M * QKV_STRIDE];  // 25088 B

    const int tid  = threadIdx.x;
    const int lane = tid & 63;
    const int wave = tid >> 6;
    const int col  = lane & 15;   // MFMA C/D col == A row (m) == B col (n)
    const int quad = lane >> 4;
    const long base_tok = (long)blockIdx.x * TILE_M;

    const int nb = wave * 6;      // this wave's 6 qkv n-tiles (both m-tiles)

    // ---- stage A: x fragments, per-m rounds (8 loads in flight)
    bf16x8 afr[2][4];
#pragma unroll
    for (int m = 0; m < 2; ++m) {
        const float* xrow = x + (base_tok + m * 16 + col) * 128;
        float4 s[4][2];
#pragma unroll
        for (int ks = 0; ks < 4; ++ks) {
            const float4* p = (const float4*)(xrow + ks * 32 + quad * 8);
            s[ks][0] = p[0];
            s[ks][1] = p[1];
        }
#pragma unroll
        for (int ks = 0; ks < 4; ++ks) {
            float4 f0 = s[ks][0], f1 = s[ks][1];
            u32x4 a = {pkbf(f0.x, f0.y), pkbf(f0.z, f0.w),
                       pkbf(f1.x, f1.y), pkbf(f1.z, f1.w)};
            afr[m][ks] = __builtin_bit_cast(bf16x8, a);
        }
    }

    // acc[m][j][r] = qkv[m*16 + quad*4 + r][(nb+j)*16 + col]; init = bias
    f32x4 acc[2][6];
#pragma unroll
    for (int j = 0; j < 6; ++j) {
        float b = bqkv[(nb + j) * 16 + col];
        acc[0][j] = (f32x4){b, b, b, b};
        acc[1][j] = (f32x4){b, b, b, b};
    }
#pragma unroll
    for (int ks = 0; ks < 4; ++ks) {
        bf16x8 bfr[6];                 // batched: 6 weight loads in flight
#pragma unroll
        for (int j = 0; j < 6; ++j)
            bfr[j] = *(const bf16x8*)&wqkvT[((nb + j) * 16 + col) * 128 + ks * 32 + quad * 8];
#pragma unroll
        for (int j = 0; j < 6; ++j) {  // each bfrag feeds 2 MFMAs
            acc[0][j] = __builtin_amdgcn_mfma_f32_16x16x32_bf16(afr[0][ks], bfr[j], acc[0][j], 0, 0, 0);
            acc[1][j] = __builtin_amdgcn_mfma_f32_16x16x32_bf16(afr[1][ks], bfr[j], acc[1][j], 0, 0, 0);
        }
    }

    // ---- transpose: qkv -> LDS bf16 [tok][ch]
#pragma unroll
    for (int m = 0; m < 2; ++m)
#pragma unroll
        for (int j = 0; j < 6; ++j)
#pragma unroll
            for (int r = 0; r < 4; ++r)
                us[(m * 16 + quad * 4 + r) * QKV_STRIDE + (nb + j) * 16 + col] = f2bf(acc[m][j][r]);
    __syncthreads();   // the ONLY barrier in k1

    // ---- stage B: thread owns (t = tid>>3, h = tid&7)
    const int t = tid >> 3;
    const int h = tid & 7;
    const unsigned short* row = us + t * QKV_STRIDE + h * 16;

    u32x4 qp0 = *(const u32x4*)(row);
    u32x4 qp1 = *(const u32x4*)(row + 8);
    u32x4 kp0 = *(const u32x4*)(row + 128);
    u32x4 kp1 = *(const u32x4*)(row + 136);
    u32x4 vp0 = *(const u32x4*)(row + 256);
    u32x4 vp1 = *(const u32x4*)(row + 264);

    const float sl2e = 0.08838834764831845f * 1.44269504088896340f; // scale*log2(e)
    float qv[16], kf[16], vf[16];
#pragma unroll
    for (int c = 0; c < 4; ++c) {
        qv[2*c]   = bflo(qp0[c]); qv[2*c+1]   = bfhi(qp0[c]);
        qv[8+2*c] = bflo(qp1[c]); qv[8+2*c+1] = bfhi(qp1[c]);
        kf[2*c]   = bflo(kp0[c]); kf[2*c+1]   = bfhi(kp0[c]);
        kf[8+2*c] = bflo(kp1[c]); kf[8+2*c+1] = bfhi(kp1[c]);
        vf[2*c]   = bflo(vp0[c]); vf[2*c+1]   = bfhi(vp0[c]);
        vf[8+2*c] = bflo(vp1[c]); vf[8+2*c+1] = bfhi(vp1[c]);
    }
    float ov[16];
#pragma unroll
    for (int i = 0; i < 16; ++i) {
        float qs = qv[i] * sl2e;
        float den = 0.f, num = 0.f;
#pragma unroll
        for (int j = 0; j < 16; ++j) {
            float e = __builtin_amdgcn_exp2f(qs * kf[j]);
            den += e;
            num = fmaf(e, vf[j], num);
        }
        ov[i] = num * __builtin_amdgcn_rcpf(den);
    }
    // pack o -> bf16, store straight to global: row t byte t*512, head h at +h*32.
    // lanes 0..7 share t -> 256 B contiguous per 8 lanes.
    u32x4 o0 = {pkbf(ov[0], ov[1]), pkbf(ov[2], ov[3]), pkbf(ov[4], ov[5]), pkbf(ov[6], ov[7])};
    u32x4 o1 = {pkbf(ov[8], ov[9]), pkbf(ov[10], ov[11]), pkbf(ov[12], ov[13]), pkbf(ov[14], ov[15])};
    char* orow = obuf + (size_t)(base_tok + t) * 512 + h * 32;
    *(u32x4*)(orow)      = o0;
    *(u32x4*)(orow + 16) = o1;
}

// ---------------- kernel 2: streaming proj GEMM ----------------
__global__ __launch_bounds__(256) void proj_gemm(
    const char* __restrict__ obuf,     // bf16 o: row t at byte t*512, 256 B
    const unsigned short* __restrict__ wprojT,
    const float* __restrict__ bproj,
    float* __restrict__ out)
{
    __shared__ __align__(16) unsigned short os[PTILE * O_STRIDE];  // 17408 B

    const int tid  = threadIdx.x;
    const int lane = tid & 63;
    const int wave = tid >> 6;
    const int col  = lane & 15;
    const int quad = lane >> 4;
    const long base = (long)blockIdx.x * PTILE;

    // ---- stage o tile: 64 rows x 256 B -> LDS stride 136 (coalesced reads)
#pragma unroll
    for (int i = 0; i < 4; ++i) {
        int q = tid + 256 * i;          // 0..1023 16B chunks
        int r = q >> 4, c = q & 15;
        u32x4 v = *(const u32x4*)(obuf + (size_t)(base + r) * 512 + c * 16);
        *(u32x4*)&os[r * O_STRIDE + c * 8] = v;
    }
    __syncthreads();

    // ---- wave: m-tile = wave, all 8 n-tiles
    bf16x8 af[4];
#pragma unroll
    for (int ks = 0; ks < 4; ++ks)
        af[ks] = *(const bf16x8*)&os[(wave * 16 + col) * O_STRIDE + ks * 32 + quad * 8];

    f32x4 acc[8];
#pragma unroll
    for (int n = 0; n < 8; ++n) {
        float b = bproj[n * 16 + col];
        acc[n] = (f32x4){b, b, b, b};
    }
#pragma unroll
    for (int ks = 0; ks < 4; ++ks) {
#pragma unroll
        for (int half = 0; half < 2; ++half) {
            bf16x8 bb[4];
#pragma unroll
            for (int n = 0; n < 4; ++n)
                bb[n] = *(const bf16x8*)&wprojT[((half * 4 + n) * 16 + col) * 128 + ks * 32 + quad * 8];
#pragma unroll
            for (int n = 0; n < 4; ++n)
                acc[half * 4 + n] = __builtin_amdgcn_mfma_f32_16x16x32_bf16(
                    af[ks], bb[n], acc[half * 4 + n], 0, 0, 0);
        }
    }
    // epilogue: fp32 store (overwrites the staged o region of THIS block only)
#pragma unroll
    for (int n = 0; n < 8; ++n)
#pragma unroll
        for (int r = 0; r < 4; ++r) {
            long tt = base + wave * 16 + quad * 4 + r;
            out[tt * 128 + n * 16 + col] = acc[n][r];
        }
}

extern "C" void kernel_launch(void* const* d_in, const int* in_sizes, int n_in,
                              void* d_out, int out_size, void* d_ws, size_t ws_size,
                              hipStream_t stream) {
    const float* x     = (const float*)d_in[0];
    const float* wqkv  = (const float*)d_in[1];
    const float* bqkv  = (const float*)d_in[2];
    const float* wproj = (const float*)d_in[3];
    const float* bproj = (const float*)d_in[4];
    float* out = (float*)d_out;

    unsigned short* wqkvT  = (unsigned short*)d_ws;    // 384*128 bf16
    unsigned short* wprojT = wqkvT + 384 * 128;        // 128*128 bf16

    prep_weights<<<192, 256, 0, stream>>>(wqkv, wproj, wqkvT, wprojT);

    const int tokens = in_sizes[0] / 128;              // 65536
    qkv_attn<<<tokens / TILE_M, 256, 0, stream>>>(
        x, wqkvT, bqkv, (char*)d_out);
    proj_gemm<<<tokens / PTILE, 256, 0, stream>>>(
        (const char*)d_out, wprojT, bproj, out);
}